// Round 4
// baseline (634.621 us; speedup 1.0000x reference)
//
#include <hip/hip_runtime.h>
#include <math.h>

#define HID 256
#define TD 32
#define NL 3
#define C1DIM 128
#define OUTDIM 2
#define QKVW 768

using half8  = __attribute__((ext_vector_type(8))) _Float16;
using half2v = __attribute__((ext_vector_type(2))) _Float16;
using f32x4  = __attribute__((ext_vector_type(4))) float;

typedef __attribute__((address_space(1))) void gbl_void_t;
typedef __attribute__((address_space(3))) void lds_void_t;

__device__ __forceinline__ void load16_to_lds(const void* g, void* l) {
  __builtin_amdgcn_global_load_lds((const gbl_void_t*)g, (lds_void_t*)l, 16, 0, 0);
}

__device__ __forceinline__ float dot8(half8 a, half8 b) {
#if __has_builtin(__builtin_amdgcn_fdot2)
  union { half8 v; half2v h2[4]; } ua, ub;
  ua.v = a; ub.v = b;
  float acc = 0.f;
#pragma unroll
  for (int j = 0; j < 4; ++j) acc = __builtin_amdgcn_fdot2(ua.h2[j], ub.h2[j], acc, false);
  return acc;
#else
  float acc = 0.f;
#pragma unroll
  for (int j = 0; j < 8; ++j) acc += (float)a[j] * (float)b[j];
  return acc;
#endif
}

// ---------- helpers ----------
__device__ __forceinline__ unsigned fkey(float f) {
  unsigned u = __float_as_uint(f);
  return (u & 0x80000000u) ? ~u : (u | 0x80000000u);
}
__device__ __forceinline__ float fdecode(unsigned k) {
  unsigned u = (k & 0x80000000u) ? (k & 0x7fffffffu) : ~k;
  return __uint_as_float(u);
}

// ---------- setup kernels ----------
__global__ void k_init(int* deg, unsigned* mm, int n) {
  int i = blockIdx.x * blockDim.x + threadIdx.x;
  if (i < n) deg[i] = 0;
  if (i == 0) { mm[0] = 0xFFFFFFFFu; mm[1] = 0u; }
}

__global__ void k_minmax(const float* __restrict__ ts, unsigned* mm, int n) {
  int i0 = blockIdx.x * blockDim.x + threadIdx.x;
  unsigned lmin = 0xFFFFFFFFu, lmax = 0u;
  for (int i = i0; i < n; i += gridDim.x * blockDim.x) {
    unsigned k = fkey(ts[i]);
    lmin = min(lmin, k); lmax = max(lmax, k);
  }
  atomicMin(&mm[0], lmin);
  atomicMax(&mm[1], lmax);
}

__global__ void k_time_enc(const float* __restrict__ ts, const float* __restrict__ freq,
                           const unsigned* __restrict__ mm, _Float16* __restrict__ tfh, int n) {
  int idx = blockIdx.x * blockDim.x + threadIdx.x;
  if (idx >= n * TD) return;
  int node = idx >> 5, j = idx & 31;
  float tmin = fdecode(mm[0]), tmax = fdecode(mm[1]);
  float t = (ts[node] - tmin) / (tmax - tmin + 1e-8f);
  float w = t * freq[j & 15];
  tfh[idx] = (_Float16)((j < 16) ? cosf(w) : sinf(w));
}

__global__ void k_cvt(const float* __restrict__ in, _Float16* __restrict__ out, int total) {
  int i = blockIdx.x * blockDim.x + threadIdx.x;
  if (i < total) out[i] = (_Float16)in[i];
}

// W[K][N] fp32 -> Wt[N][K] fp16
__global__ void k_wt(const float* __restrict__ W, _Float16* __restrict__ Wt,
                     int K, int N, int total) {
  int idx = blockIdx.x * blockDim.x + threadIdx.x;
  if (idx >= total) return;
  int mat = idx / (K * N);
  int rem = idx - mat * (K * N);
  int nrow = rem / K;
  int k = rem - nrow * K;
  Wt[idx] = (_Float16)W[(size_t)mat * K * N + (size_t)k * N + nrow];
}

// fused QKV weight: out[L][768][288]
__global__ void k_wt_qkv(const float* __restrict__ qW, const float* __restrict__ kW,
                         const float* __restrict__ vW, _Float16* __restrict__ Wt, int total) {
  int idx = blockIdx.x * blockDim.x + threadIdx.x;
  if (idx >= total) return;
  const int KQ = HID + TD;
  int l = idx / (QKVW * KQ);
  int rem = idx - l * (QKVW * KQ);
  int nrow = rem / KQ;
  int k = rem - nrow * KQ;
  float v;
  if (nrow < 256)      v = qW[(size_t)l * KQ * HID + (size_t)k * HID + nrow];
  else if (nrow < 512) v = kW[(size_t)l * KQ * HID + (size_t)k * HID + (nrow - 256)];
  else                 v = (k < HID) ? vW[(size_t)l * HID * HID + (size_t)k * HID + (nrow - 512)] : 0.f;
  Wt[idx] = (_Float16)v;
}

__global__ void k_fuse_bias(const float* __restrict__ qb, const float* __restrict__ kb,
                            const float* __restrict__ vb, float* __restrict__ out, int total) {
  int idx = blockIdx.x * blockDim.x + threadIdx.x;
  if (idx >= total) return;
  int l = idx / QKVW;
  int j = idx - l * QKVW;
  float v;
  if (j < 256)      v = qb[l * HID + j];
  else if (j < 512) v = kb[l * HID + (j - 256)];
  else              v = vb[l * HID + (j - 512)];
  out[idx] = v;
}

__global__ void k_count(const int* __restrict__ dst, int* deg, int e) {
  int i = blockIdx.x * blockDim.x + threadIdx.x;
  if (i < e) atomicAdd(&deg[dst[i]], 1);
}

__global__ __launch_bounds__(1024) void k_scan(const int* __restrict__ deg,
                                               int* __restrict__ row_ptr,
                                               int* __restrict__ cursor, int n) {
  __shared__ int wsum[16];
  __shared__ int s_carry;
  int t = threadIdx.x;
  int lane = t & 63, wid = t >> 6;
  if (t == 0) s_carry = 0;
  __syncthreads();
  for (int base = 0; base < n; base += 1024) {
    int idx = base + t;
    int v = (idx < n) ? deg[idx] : 0;
    int x = v;
#pragma unroll
    for (int off = 1; off < 64; off <<= 1) {
      int y = __shfl_up(x, off);
      if (lane >= off) x += y;
    }
    if (lane == 63) wsum[wid] = x;
    __syncthreads();
    if (wid == 0) {
      int w = (lane < 16) ? wsum[lane] : 0;
#pragma unroll
      for (int off = 1; off < 16; off <<= 1) {
        int y = __shfl_up(w, off);
        if (lane >= off) w += y;
      }
      if (lane < 16) wsum[lane] = w;
    }
    __syncthreads();
    int wprev = (wid > 0) ? wsum[wid - 1] : 0;
    int incl = x + wprev;
    int carry = s_carry;
    if (idx < n) { row_ptr[idx] = carry + incl - v; cursor[idx] = 0; }
    __syncthreads();
    if (t == 1023) s_carry = carry + incl;
    __syncthreads();
  }
  if (t == 0) row_ptr[n] = s_carry;
}

__global__ void k_scatter(const int* __restrict__ src, const int* __restrict__ dst,
                          const int* __restrict__ row_ptr, int* cursor,
                          int* __restrict__ colbuf, int e) {
  int i = blockIdx.x * blockDim.x + threadIdx.x;
  if (i >= e) return;
  int d = dst[i];
  int p = atomicAdd(&cursor[d], 1);
  colbuf[row_ptr[d] + p] = src[i];
}

// ---------- fp16 MFMA GEMM, 128x128 tile, BK=32, 4 waves (each 64x64) ----------
__global__ __launch_bounds__(256) void k_gemm_f16(
    const _Float16* __restrict__ A1, int K1,
    const _Float16* __restrict__ A2, int K2,
    const _Float16* __restrict__ Bt,
    const float* __restrict__ bias,
    _Float16* __restrict__ C,
    int M, int Ncols, int Ktot, int act) {
  __shared__ half8 smem8[2048];  // 2 bufs x (8KB A + 8KB B) = 32KB
  char* smem = (char*)smem8;
  const int tid = threadIdx.x;
  const int lane = tid & 63, wave = tid >> 6;
  const int wm = wave >> 1, wn = wave & 1;
  const int row0 = blockIdx.y * 128;
  const int col0 = blockIdx.x * 128;

  // LDS layout: A slot = kg*128 + row (kg=k-group of 8, 16B each); B slot = kg*128 + col
  auto stage = [&](int buf, int k0) {
    char* sA = smem + buf * 16384;
    char* sB = sA + 8192;
    int k = k0 + wave * 8;  // wave stages its own kg
    const _Float16* srcA;
#pragma unroll
    for (int j = 0; j < 2; ++j) {
      int row = j * 64 + lane;
      int grow = row0 + row; if (grow > M - 1) grow = M - 1;
      srcA = (k < K1) ? (A1 + (size_t)grow * K1 + k)
                      : (A2 + (size_t)grow * K2 + (k - K1));
      load16_to_lds(srcA, sA + (wave * 128 + j * 64) * 16);
    }
#pragma unroll
    for (int j = 0; j < 2; ++j) {
      int col = j * 64 + lane;
      const _Float16* srcB = Bt + (size_t)(col0 + col) * Ktot + k;
      load16_to_lds(srcB, sB + (wave * 128 + j * 64) * 16);
    }
  };

  f32x4 acc[4][4];
#pragma unroll
  for (int mf = 0; mf < 4; ++mf)
#pragma unroll
    for (int nf = 0; nf < 4; ++nf) acc[mf][nf] = f32x4{0.f, 0.f, 0.f, 0.f};

  const int nsteps = Ktot >> 5;
  int cur = 0;
  stage(0, 0);
  __syncthreads();
  for (int st = 0; st < nsteps; ++st) {
    if (st + 1 < nsteps) stage(cur ^ 1, (st + 1) * 32);
    char* sA = smem + cur * 16384;
    char* sB = sA + 8192;
    half8 af[4], bf[4];
#pragma unroll
    for (int mf = 0; mf < 4; ++mf) {
      int slot = (lane >> 4) * 128 + wm * 64 + mf * 16 + (lane & 15);
      af[mf] = *(const half8*)(sA + slot * 16);
    }
#pragma unroll
    for (int nf = 0; nf < 4; ++nf) {
      int slot = (lane >> 4) * 128 + wn * 64 + nf * 16 + (lane & 15);
      bf[nf] = *(const half8*)(sB + slot * 16);
    }
#pragma unroll
    for (int mf = 0; mf < 4; ++mf)
#pragma unroll
      for (int nf = 0; nf < 4; ++nf)
        acc[mf][nf] = __builtin_amdgcn_mfma_f32_16x16x32_f16(af[mf], bf[nf], acc[mf][nf], 0, 0, 0);
    __syncthreads();
    cur ^= 1;
  }

  const int rbase = row0 + wm * 64 + (lane >> 4) * 4;
  const int cbase = col0 + wn * 64 + (lane & 15);
#pragma unroll
  for (int nf = 0; nf < 4; ++nf) {
    int col = cbase + nf * 16;
    float bv = bias[col];
#pragma unroll
    for (int mf = 0; mf < 4; ++mf) {
#pragma unroll
      for (int r = 0; r < 4; ++r) {
        int row = rbase + mf * 16 + r;
        if (row < M) {
          float v = acc[mf][nf][r] + bv;
          if (act == 1) v = (v > 0.f) ? v : expm1f(v);
          C[(size_t)row * Ncols + col] = (_Float16)v;
        }
      }
    }
  }
}

// ---------- fused per-node edge attention, double-buffered 4-edge chunks ----------
// QKV[n][768]: Q|K|V. 32 threads/node (8 dims each), 8 nodes/block.
__global__ __launch_bounds__(256) void k_attn(const _Float16* __restrict__ QKV,
                                              const int* __restrict__ row_ptr,
                                              const int* __restrict__ colbuf,
                                              _Float16* __restrict__ out, int n) {
  int node = blockIdx.x * 8 + (threadIdx.x >> 5);
  if (node >= n) return;
  int t32 = threadIdx.x & 31;
  int d = t32 * 8;
  const float scale = 0.17677669529663687f;  // 1/sqrt(32)
  half8 qh = *(const half8*)(QKV + (size_t)node * QKVW + d);
#pragma unroll
  for (int j = 0; j < 8; ++j) qh[j] = (_Float16)((float)qh[j] * scale);

  int beg = row_ptr[node], end = row_ptr[node + 1];
  float m = -INFINITY, s = 0.f;
  float a[8] = {0.f, 0.f, 0.f, 0.f, 0.f, 0.f, 0.f, 0.f};

  auto update = [&](float score, half8 vh) {
    if (score <= m) {
      float e = __expf(score - m);
      s += e;
#pragma unroll
      for (int j = 0; j < 8; ++j) a[j] = fmaf(e, (float)vh[j], a[j]);
    } else {
      float f = __expf(m - score);  // m=-inf first real edge -> f=0
      s = s * f + 1.f;
#pragma unroll
      for (int j = 0; j < 8; ++j) a[j] = fmaf(a[j], f, (float)vh[j]);
      m = score;
    }
  };

  auto loadChunk = [&](int base, half8 (&kk)[4], half8 (&vv)[4]) {
#pragma unroll
    for (int j = 0; j < 4; ++j) {
      int idx = base + j;
      int sidx = (idx < end) ? colbuf[idx] : 0;
      const _Float16* b = QKV + (size_t)sidx * QKVW + d;
      kk[j] = *(const half8*)(b + 256);
      vv[j] = *(const half8*)(b + 512);
    }
  };

  auto computeChunk = [&](int base, half8 (&kk)[4], half8 (&vv)[4]) {
    float p[4];
#pragma unroll
    for (int j = 0; j < 4; ++j) p[j] = dot8(qh, kk[j]);
#pragma unroll
    for (int j = 0; j < 4; ++j) {
      p[j] += __shfl_xor(p[j], 1);
      p[j] += __shfl_xor(p[j], 2);
      if (base + j >= end) p[j] = -INFINITY;  // masked pad: exp -> 0
    }
#pragma unroll
    for (int j = 0; j < 4; ++j) update(p[j], vv[j]);
  };

  half8 kA[4], vA[4], kB[4], vB[4];
  int i = beg;
  loadChunk(i, kA, vA);
  loadChunk(i + 4, kB, vB);
  for (; i < end; i += 8) {
    computeChunk(i, kA, vA);
    loadChunk(i + 8, kA, vA);
    computeChunk(i + 4, kB, vB);
    loadChunk(i + 12, kB, vB);
  }

  half8 o;
  float inv = (s > 0.f) ? (1.f / s) : 0.f;
#pragma unroll
  for (int j = 0; j < 8; ++j) o[j] = (_Float16)(a[j] * inv);
  *(half8*)(out + (size_t)node * HID + d) = o;
}

// ---------- pooling + classifier ----------
__global__ __launch_bounds__(256) void k_pool_partial(const _Float16* __restrict__ h,
                                                      float* __restrict__ partial, int n) {
  int b = blockIdx.x, t = threadIdx.x;
  float s = 0.f;
  for (int r = b; r < n; r += 256) s += (float)h[(size_t)r * HID + t];
  partial[b * HID + t] = s;
}

__global__ __launch_bounds__(256) void k_final(const float* __restrict__ partial,
                                               const float* __restrict__ c1W,
                                               const float* __restrict__ c1b,
                                               const float* __restrict__ c2W,
                                               const float* __restrict__ c2b,
                                               float* __restrict__ out, int n) {
  __shared__ float gl[HID];
  __shared__ float r1[C1DIM];
  int t = threadIdx.x;
  float s = 0.f;
  for (int b = 0; b < 256; b++) s += partial[b * HID + t];
  gl[t] = s / (float)n;
  __syncthreads();
  if (t < C1DIM) {
    float a = c1b[t];
    for (int k = 0; k < HID; k++) a += gl[k] * c1W[k * C1DIM + t];
    r1[t] = fmaxf(a, 0.f);
  }
  __syncthreads();
  if (t < OUTDIM) {
    float a = c2b[t];
    for (int k = 0; k < C1DIM; k++) a += r1[k] * c2W[k * OUTDIM + t];
    out[t] = a;
  }
}

// ---------- host launcher ----------
extern "C" void kernel_launch(void* const* d_in, const int* in_sizes, int n_in,
                              void* d_out, int out_size, void* d_ws, size_t ws_size,
                              hipStream_t stream) {
  const float* x    = (const float*)d_in[0];
  const float* ts   = (const float*)d_in[1];
  const int*   ei   = (const int*)d_in[2];
  const float* freq = (const float*)d_in[4];
  const float* inW  = (const float*)d_in[5];
  const float* inb  = (const float*)d_in[6];
  const float* qW   = (const float*)d_in[7];
  const float* qb   = (const float*)d_in[8];
  const float* kW   = (const float*)d_in[9];
  const float* kb   = (const float*)d_in[10];
  const float* vW   = (const float*)d_in[11];
  const float* vb   = (const float*)d_in[12];
  const float* oW   = (const float*)d_in[13];
  const float* ob   = (const float*)d_in[14];
  const float* c1W  = (const float*)d_in[15];
  const float* c1b  = (const float*)d_in[16];
  const float* c2W  = (const float*)d_in[17];
  const float* c2b  = (const float*)d_in[18];

  int n = in_sizes[1];
  int e = in_sizes[2] / 2;
  const int* src = ei;
  const int* dst = ei + e;

  char* w = (char*)d_ws;
  size_t off = 0;
  auto alloc = [&](size_t bytes) -> char* {
    char* p = w + off;
    off = (off + bytes + 255) & ~(size_t)255;
    return p;
  };
  _Float16* tfh     = (_Float16*)alloc((size_t)n * TD * 2);
  _Float16* xh      = (_Float16*)alloc((size_t)n * 32 * 2);
  _Float16* h       = (_Float16*)alloc((size_t)n * HID * 2);
  _Float16* QKV     = (_Float16*)alloc((size_t)n * QKVW * 2);
  _Float16* ao      = (_Float16*)alloc((size_t)n * HID * 2);
  _Float16* inWt    = (_Float16*)alloc((size_t)32 * HID * 2);
  _Float16* qkvWt   = (_Float16*)alloc((size_t)NL * QKVW * (HID + TD) * 2);
  float*    qkvb    = (float*)alloc((size_t)NL * QKVW * 4);
  _Float16* oWt     = (_Float16*)alloc((size_t)NL * HID * HID * 2);
  int*      deg     = (int*)alloc((size_t)n * 4);
  int*      cursor  = (int*)alloc((size_t)n * 4);
  int*      row_ptr = (int*)alloc((size_t)(n + 1) * 4);
  int*      colbuf  = (int*)alloc((size_t)e * 4);
  float*    partial = (float*)alloc((size_t)256 * HID * 4);
  unsigned* mm      = (unsigned*)alloc(256);

  int b256 = 256;
  hipLaunchKernelGGL(k_init, dim3((n + 255) / 256), dim3(b256), 0, stream, deg, mm, n);
  hipLaunchKernelGGL(k_minmax, dim3(40), dim3(b256), 0, stream, ts, mm, n);
  hipLaunchKernelGGL(k_time_enc, dim3((n * TD + 255) / 256), dim3(b256), 0, stream, ts, freq, mm, tfh, n);
  hipLaunchKernelGGL(k_cvt, dim3((n * 32 + 255) / 256), dim3(b256), 0, stream, x, xh, n * 32);
  hipLaunchKernelGGL(k_wt, dim3((32 * HID + 255) / 256), dim3(b256), 0, stream, inW, inWt, 32, HID, 32 * HID);
  {
    int tq = NL * QKVW * (HID + TD);
    hipLaunchKernelGGL(k_wt_qkv, dim3((tq + 255) / 256), dim3(b256), 0, stream, qW, kW, vW, qkvWt, tq);
    int tb = NL * QKVW;
    hipLaunchKernelGGL(k_fuse_bias, dim3((tb + 255) / 256), dim3(b256), 0, stream, qb, kb, vb, qkvb, tb);
    int tv = NL * HID * HID;
    hipLaunchKernelGGL(k_wt, dim3((tv + 255) / 256), dim3(b256), 0, stream, oW, oWt, HID, HID, tv);
  }
  hipLaunchKernelGGL(k_count, dim3((e + 255) / 256), dim3(b256), 0, stream, dst, deg, e);
  hipLaunchKernelGGL(k_scan, dim3(1), dim3(1024), 0, stream, deg, row_ptr, cursor, n);
  hipLaunchKernelGGL(k_scatter, dim3((e + 255) / 256), dim3(b256), 0, stream, src, dst, row_ptr, cursor, colbuf, e);

  dim3 ggrid_h(HID / 128, (n + 127) / 128);
  dim3 ggrid_qkv(QKVW / 128, (n + 127) / 128);
  hipLaunchKernelGGL(k_gemm_f16, ggrid_h, dim3(b256), 0, stream,
                     xh, 32, xh, 32, inWt, inb, h, n, HID, 32, 0);

  for (int l = 0; l < NL; ++l) {
    const _Float16* qkvWtl = qkvWt + (size_t)l * QKVW * (HID + TD);
    const float*    qkvbl  = qkvb + (size_t)l * QKVW;
    const _Float16* oWtl   = oWt + (size_t)l * HID * HID;
    hipLaunchKernelGGL(k_gemm_f16, ggrid_qkv, dim3(b256), 0, stream,
                       h, HID, tfh, TD, qkvWtl, qkvbl, QKV, n, QKVW, HID + TD, 0);
    hipLaunchKernelGGL(k_attn, dim3((n + 7) / 8), dim3(b256), 0, stream,
                       QKV, row_ptr, colbuf, ao, n);
    hipLaunchKernelGGL(k_gemm_f16, ggrid_h, dim3(b256), 0, stream,
                       ao, HID, ao, HID, oWtl, ob + l * HID, h, n, HID, HID, 1);
  }

  hipLaunchKernelGGL(k_pool_partial, dim3(256), dim3(b256), 0, stream, h, partial, n);
  hipLaunchKernelGGL(k_final, dim3(1), dim3(b256), 0, stream, partial, c1W, c1b, c2W, c2b, (float*)d_out, n);
}

// Round 5
// 575.449 us; speedup vs baseline: 1.1028x; 1.1028x over previous
//
#include <hip/hip_runtime.h>
#include <math.h>

#define HID 256
#define TD 32
#define NL 3
#define C1DIM 128
#define OUTDIM 2
#define QKVW 768

using half8  = __attribute__((ext_vector_type(8))) _Float16;
using half2v = __attribute__((ext_vector_type(2))) _Float16;
using f32x4  = __attribute__((ext_vector_type(4))) float;

typedef __attribute__((address_space(1))) void gbl_void_t;
typedef __attribute__((address_space(3))) void lds_void_t;

__device__ __forceinline__ void load16_to_lds(const void* g, void* l) {
  __builtin_amdgcn_global_load_lds((const gbl_void_t*)g, (lds_void_t*)l, 16, 0, 0);
}

__device__ __forceinline__ float dot8(half8 a, half8 b) {
#if __has_builtin(__builtin_amdgcn_fdot2)
  union { half8 v; half2v h2[4]; } ua, ub;
  ua.v = a; ub.v = b;
  float acc = 0.f;
#pragma unroll
  for (int j = 0; j < 4; ++j) acc = __builtin_amdgcn_fdot2(ua.h2[j], ub.h2[j], acc, false);
  return acc;
#else
  float acc = 0.f;
#pragma unroll
  for (int j = 0; j < 8; ++j) acc += (float)a[j] * (float)b[j];
  return acc;
#endif
}

// ---------- setup: ts min/max (single block, no atomics) + zero deg ----------
__global__ __launch_bounds__(1024) void k_tsmm(const float* __restrict__ ts,
                                               float* __restrict__ mmf,
                                               int* __restrict__ deg, int n) {
  int t = threadIdx.x;
  float lmin = INFINITY, lmax = -INFINITY;
  for (int i = t; i < n; i += 1024) {
    float v = ts[i];
    lmin = fminf(lmin, v);
    lmax = fmaxf(lmax, v);
    deg[i] = 0;
  }
#pragma unroll
  for (int off = 32; off >= 1; off >>= 1) {
    lmin = fminf(lmin, __shfl_xor(lmin, off));
    lmax = fmaxf(lmax, __shfl_xor(lmax, off));
  }
  __shared__ float wmin[16], wmax[16];
  int lane = t & 63, w = t >> 6;
  if (lane == 0) { wmin[w] = lmin; wmax[w] = lmax; }
  __syncthreads();
  if (t == 0) {
    float a = INFINITY, b = -INFINITY;
    for (int i = 0; i < 16; ++i) { a = fminf(a, wmin[i]); b = fmaxf(b, wmax[i]); }
    mmf[0] = a; mmf[1] = b;
  }
}

// ---------- merged time encoding + x conversion ----------
__global__ void k_enc(const float* __restrict__ ts, const float* __restrict__ freq,
                      const float* __restrict__ mmf, const float* __restrict__ x,
                      _Float16* __restrict__ tfh, _Float16* __restrict__ xh, int n) {
  int idx = blockIdx.x * blockDim.x + threadIdx.x;
  int nt = n * TD;
  if (idx < nt) {
    int node = idx >> 5, j = idx & 31;
    float t = (ts[node] - mmf[0]) / (mmf[1] - mmf[0] + 1e-8f);
    float w = t * freq[j & 15];
    tfh[idx] = (_Float16)((j < 16) ? cosf(w) : sinf(w));
  } else if (idx < nt + n * 32) {
    int i2 = idx - nt;
    xh[i2] = (_Float16)x[i2];
  }
}

// ---------- merged weight prep: inWt, qkvWt, qkvb, oWt ----------
__global__ void k_prep(const float* __restrict__ inW, const float* __restrict__ qW,
                       const float* __restrict__ kW, const float* __restrict__ vW,
                       const float* __restrict__ oW, const float* __restrict__ qb,
                       const float* __restrict__ kb, const float* __restrict__ vb,
                       _Float16* __restrict__ inWt, _Float16* __restrict__ qkvWt,
                       float* __restrict__ qkvb, _Float16* __restrict__ oWt) {
  int idx = blockIdx.x * blockDim.x + threadIdx.x;
  const int S0 = 32 * HID;
  const int KQ = HID + TD;
  const int S1 = NL * QKVW * KQ;
  const int S2 = NL * QKVW;
  const int S3 = NL * HID * HID;
  if (idx < S0) {
    int nrow = idx / 32, k = idx - nrow * 32;
    inWt[idx] = (_Float16)inW[k * HID + nrow];
  } else if ((idx -= S0) < S1) {
    int l = idx / (QKVW * KQ);
    int rem = idx - l * (QKVW * KQ);
    int nrow = rem / KQ;
    int k = rem - nrow * KQ;
    float v;
    if (nrow < 256)      v = qW[(size_t)l * KQ * HID + (size_t)k * HID + nrow];
    else if (nrow < 512) v = kW[(size_t)l * KQ * HID + (size_t)k * HID + (nrow - 256)];
    else                 v = (k < HID) ? vW[(size_t)l * HID * HID + (size_t)k * HID + (nrow - 512)] : 0.f;
    qkvWt[idx] = (_Float16)v;
  } else if ((idx -= S1) < S2) {
    int l = idx / QKVW;
    int j = idx - l * QKVW;
    float v;
    if (j < 256)      v = qb[l * HID + j];
    else if (j < 512) v = kb[l * HID + (j - 256)];
    else              v = vb[l * HID + (j - 512)];
    qkvb[idx] = v;
  } else if ((idx -= S2) < S3) {
    int l = idx / (HID * HID);
    int rem = idx - l * (HID * HID);
    int nrow = rem / HID;
    int k = rem - nrow * HID;
    oWt[idx] = (_Float16)oW[(size_t)l * HID * HID + (size_t)k * HID + nrow];
  }
}

__global__ void k_count(const int* __restrict__ dst, int* deg, int e) {
  int i = blockIdx.x * blockDim.x + threadIdx.x;
  if (i < e) atomicAdd(&deg[dst[i]], 1);
}

// ---------- 3-kernel scan ----------
__global__ __launch_bounds__(256) void k_scan_part(const int* __restrict__ deg,
                                                   int* __restrict__ bsum, int n) {
  int t = threadIdx.x;
  int idx = blockIdx.x * 256 + t;
  int v = (idx < n) ? deg[idx] : 0;
  int lane = t & 63, w = t >> 6;
  int x = v;
#pragma unroll
  for (int off = 1; off < 64; off <<= 1) {
    int y = __shfl_up(x, off);
    if (lane >= off) x += y;
  }
  __shared__ int ws[4];
  if (lane == 63) ws[w] = x;
  __syncthreads();
  if (t == 0) bsum[blockIdx.x] = ws[0] + ws[1] + ws[2] + ws[3];
}

__global__ __launch_bounds__(64) void k_scan_mid(const int* __restrict__ bsum,
                                                 int* __restrict__ boff, int nb) {
  int lane = threadIdx.x;
  int carry = 0;
  for (int base = 0; base < nb; base += 64) {
    int i = base + lane;
    int v = (i < nb) ? bsum[i] : 0;
    int x = v;
#pragma unroll
    for (int off = 1; off < 64; off <<= 1) {
      int y = __shfl_up(x, off);
      if (lane >= off) x += y;
    }
    if (i < nb) boff[i] = carry + x - v;
    carry += __shfl(x, 63);
  }
}

__global__ __launch_bounds__(256) void k_scan_apply(const int* __restrict__ deg,
                                                    const int* __restrict__ boff,
                                                    int* __restrict__ row_ptr,
                                                    int* __restrict__ cursor, int n, int e) {
  int t = threadIdx.x;
  int idx = blockIdx.x * 256 + t;
  int v = (idx < n) ? deg[idx] : 0;
  int lane = t & 63, w = t >> 6;
  int x = v;
#pragma unroll
  for (int off = 1; off < 64; off <<= 1) {
    int y = __shfl_up(x, off);
    if (lane >= off) x += y;
  }
  __shared__ int ws[4];
  if (lane == 63) ws[w] = x;
  __syncthreads();
  int wpre = 0;
  for (int i = 0; i < w; ++i) wpre += ws[i];
  if (idx < n) {
    row_ptr[idx] = boff[blockIdx.x] + wpre + x - v;
    cursor[idx] = 0;
  }
  if (idx == 0) row_ptr[n] = e;
}

__global__ void k_scatter(const int* __restrict__ src, const int* __restrict__ dst,
                          const int* __restrict__ row_ptr, int* cursor,
                          int* __restrict__ colbuf, int e) {
  int i = blockIdx.x * blockDim.x + threadIdx.x;
  if (i >= e) return;
  int d = dst[i];
  int p = atomicAdd(&cursor[d], 1);
  colbuf[row_ptr[d] + p] = src[i];
}

// ---------- fp16 MFMA GEMM (R3 geometry: 128x64 tile, BK=32, 4 waves) ----------
__global__ __launch_bounds__(256) void k_gemm_f16(
    const _Float16* __restrict__ A1, int K1,
    const _Float16* __restrict__ A2, int K2,
    const _Float16* __restrict__ Bt,
    const float* __restrict__ bias,
    _Float16* __restrict__ C,
    int M, int Ncols, int Ktot, int act) {
  __shared__ half8 smem8[2 * 768];
  char* smem = (char*)smem8;
  const int tid = threadIdx.x;
  const int lane = tid & 63, wave = tid >> 6;
  const int wm = wave >> 1, wn = wave & 1;
  const int row0 = blockIdx.y * 128;
  const int col0 = blockIdx.x * 64;

  auto stage = [&](int buf, int k0) {
    char* sA = smem + buf * 12288;
    char* sB = sA + 8192;
#pragma unroll
    for (int i = 0; i < 2; ++i) {
      int kg = i * 2 + (wave >> 1);
      int row = (wave & 1) * 64 + lane;
      int grow = row0 + row; if (grow > M - 1) grow = M - 1;
      int k = k0 + kg * 8;
      const _Float16* src = (k < K1) ? (A1 + (size_t)grow * K1 + k)
                                     : (A2 + (size_t)grow * K2 + (k - K1));
      load16_to_lds(src, sA + (i * 256 + wave * 64) * 16);
    }
    {
      const _Float16* src = Bt + (size_t)(col0 + lane) * Ktot + k0 + wave * 8;
      load16_to_lds(src, sB + wave * 64 * 16);
    }
  };

  f32x4 acc[4][2];
#pragma unroll
  for (int mf = 0; mf < 4; ++mf)
#pragma unroll
    for (int nf = 0; nf < 2; ++nf) acc[mf][nf] = f32x4{0.f, 0.f, 0.f, 0.f};

  const int nsteps = Ktot >> 5;
  int cur = 0;
  stage(0, 0);
  __syncthreads();
  for (int st = 0; st < nsteps; ++st) {
    if (st + 1 < nsteps) stage(cur ^ 1, (st + 1) * 32);
    char* sA = smem + cur * 12288;
    char* sB = sA + 8192;
    half8 af[4], bf[2];
#pragma unroll
    for (int mf = 0; mf < 4; ++mf) {
      int slot = (lane >> 4) * 128 + wm * 64 + mf * 16 + (lane & 15);
      af[mf] = *(const half8*)(sA + slot * 16);
    }
#pragma unroll
    for (int nf = 0; nf < 2; ++nf) {
      int slot = (lane >> 4) * 64 + wn * 32 + nf * 16 + (lane & 15);
      bf[nf] = *(const half8*)(sB + slot * 16);
    }
#pragma unroll
    for (int mf = 0; mf < 4; ++mf)
#pragma unroll
      for (int nf = 0; nf < 2; ++nf)
        acc[mf][nf] = __builtin_amdgcn_mfma_f32_16x16x32_f16(af[mf], bf[nf], acc[mf][nf], 0, 0, 0);
    __syncthreads();
    cur ^= 1;
  }

  const int rbase = row0 + wm * 64 + (lane >> 4) * 4;
  const int cbase = col0 + wn * 32 + (lane & 15);
#pragma unroll
  for (int nf = 0; nf < 2; ++nf) {
    int col = cbase + nf * 16;
    float bv = bias[col];
#pragma unroll
    for (int mf = 0; mf < 4; ++mf) {
#pragma unroll
      for (int r = 0; r < 4; ++r) {
        int row = rbase + mf * 16 + r;
        if (row < M) {
          float v = acc[mf][nf][r] + bv;
          if (act == 1) v = (v > 0.f) ? v : expm1f(v);
          C[(size_t)row * Ncols + col] = (_Float16)v;
        }
      }
    }
  }
}

// ---------- attention: 2 groups per node (split edge list), LSE-merge in LDS ----------
// block = 256 = 8 groups of 32 threads; 4 nodes/block; grid = ceil(n/4)
__global__ __launch_bounds__(256) void k_attn(const _Float16* __restrict__ QKV,
                                              const int* __restrict__ row_ptr,
                                              const int* __restrict__ colbuf,
                                              _Float16* __restrict__ out, int n) {
  __shared__ float sm_m[4][8], sm_s[4][8];
  __shared__ float sm_a[4][32][9];
  int tid = threadIdx.x;
  int g = tid >> 5, t32 = tid & 31;
  int nl = g >> 1, hf = g & 1;
  int node = blockIdx.x * 4 + nl;
  bool act = node < n;
  int beg = 0, end = 0;
  if (act) { beg = row_ptr[node]; end = row_ptr[node + 1]; }
  int mid = beg + ((end - beg + 1) >> 1);
  int lo = hf ? mid : beg;
  int hi = hf ? end : mid;
  int d = t32 * 8;
  const float scale = 0.17677669529663687f;  // 1/sqrt(32)
  half8 qh = {};
  if (act) {
    qh = *(const half8*)(QKV + (size_t)node * QKVW + d);
#pragma unroll
    for (int j = 0; j < 8; ++j) qh[j] = (_Float16)((float)qh[j] * scale);
  }
  float m = -INFINITY, s = 0.f;
  float a[8] = {0.f, 0.f, 0.f, 0.f, 0.f, 0.f, 0.f, 0.f};

  for (int i = lo; i < hi; i += 4) {
    half8 kk[4], vv[4];
#pragma unroll
    for (int j = 0; j < 4; ++j) {
      int ii = i + j; if (ii > hi - 1) ii = hi - 1;
      int sn = colbuf[ii];
      const _Float16* bq = QKV + (size_t)sn * QKVW + d;
      kk[j] = *(const half8*)(bq + 256);
      vv[j] = *(const half8*)(bq + 512);
    }
    float p[4];
#pragma unroll
    for (int j = 0; j < 4; ++j) p[j] = dot8(qh, kk[j]);
#pragma unroll
    for (int j = 0; j < 4; ++j) {
      p[j] += __shfl_xor(p[j], 1);
      p[j] += __shfl_xor(p[j], 2);
      if (i + j >= hi) p[j] = -INFINITY;  // tail mask (first edge of chunk is always real)
    }
#pragma unroll
    for (int j = 0; j < 4; ++j) {
      float sc = p[j];
      if (sc <= m) {
        float e2 = __expf(sc - m);
        s += e2;
#pragma unroll
        for (int q = 0; q < 8; ++q) a[q] = fmaf(e2, (float)vv[j][q], a[q]);
      } else {
        float f = __expf(m - sc);  // m=-inf on first real edge -> f=0
        s = s * f + 1.f;
#pragma unroll
        for (int q = 0; q < 8; ++q) a[q] = fmaf(a[q], f, (float)vv[j][q]);
        m = sc;
      }
    }
  }

  if (hf == 1 && act) {
    if ((t32 & 3) == 0) { sm_m[nl][t32 >> 2] = m; sm_s[nl][t32 >> 2] = s; }
#pragma unroll
    for (int q = 0; q < 8; ++q) sm_a[nl][t32][q] = a[q];
  }
  __syncthreads();
  if (hf == 0 && act) {
    float m1 = sm_m[nl][t32 >> 2], s1 = sm_s[nl][t32 >> 2];
    float M = fmaxf(m, m1);
    float f0 = (s > 0.f) ? __expf(m - M) : 0.f;
    float f1 = (s1 > 0.f) ? __expf(m1 - M) : 0.f;
    float S = s * f0 + s1 * f1;
    float inv = (S > 0.f) ? (1.f / S) : 0.f;
    half8 o;
#pragma unroll
    for (int q = 0; q < 8; ++q) o[q] = (_Float16)((a[q] * f0 + sm_a[nl][t32][q] * f1) * inv);
    *(half8*)(out + (size_t)node * HID + d) = o;
  }
}

// ---------- pooling + classifier ----------
__global__ __launch_bounds__(256) void k_pool_partial(const _Float16* __restrict__ h,
                                                      float* __restrict__ partial, int n) {
  int b = blockIdx.x, t = threadIdx.x;
  float s = 0.f;
  for (int r = b; r < n; r += 256) s += (float)h[(size_t)r * HID + t];
  partial[b * HID + t] = s;
}

__global__ __launch_bounds__(256) void k_final(const float* __restrict__ partial,
                                               const float* __restrict__ c1W,
                                               const float* __restrict__ c1b,
                                               const float* __restrict__ c2W,
                                               const float* __restrict__ c2b,
                                               float* __restrict__ out, int n) {
  __shared__ float gl[HID];
  __shared__ float r1[C1DIM];
  int t = threadIdx.x;
  float s = 0.f;
  for (int b = 0; b < 256; b++) s += partial[b * HID + t];
  gl[t] = s / (float)n;
  __syncthreads();
  if (t < C1DIM) {
    float a = c1b[t];
    for (int k = 0; k < HID; k++) a += gl[k] * c1W[k * C1DIM + t];
    r1[t] = fmaxf(a, 0.f);
  }
  __syncthreads();
  if (t < OUTDIM) {
    float a = c2b[t];
    for (int k = 0; k < C1DIM; k++) a += r1[k] * c2W[k * OUTDIM + t];
    out[t] = a;
  }
}

// ---------- host launcher ----------
extern "C" void kernel_launch(void* const* d_in, const int* in_sizes, int n_in,
                              void* d_out, int out_size, void* d_ws, size_t ws_size,
                              hipStream_t stream) {
  const float* x    = (const float*)d_in[0];
  const float* ts   = (const float*)d_in[1];
  const int*   ei   = (const int*)d_in[2];
  const float* freq = (const float*)d_in[4];
  const float* inW  = (const float*)d_in[5];
  const float* inb  = (const float*)d_in[6];
  const float* qW   = (const float*)d_in[7];
  const float* qb   = (const float*)d_in[8];
  const float* kW   = (const float*)d_in[9];
  const float* kb   = (const float*)d_in[10];
  const float* vW   = (const float*)d_in[11];
  const float* vb   = (const float*)d_in[12];
  const float* oW   = (const float*)d_in[13];
  const float* ob   = (const float*)d_in[14];
  const float* c1W  = (const float*)d_in[15];
  const float* c1b  = (const float*)d_in[16];
  const float* c2W  = (const float*)d_in[17];
  const float* c2b  = (const float*)d_in[18];

  int n = in_sizes[1];
  int e = in_sizes[2] / 2;
  const int* src = ei;
  const int* dst = ei + e;
  int nb = (n + 255) / 256;

  char* w = (char*)d_ws;
  size_t off = 0;
  auto alloc = [&](size_t bytes) -> char* {
    char* p = w + off;
    off = (off + bytes + 255) & ~(size_t)255;
    return p;
  };
  _Float16* tfh     = (_Float16*)alloc((size_t)n * TD * 2);
  _Float16* xh      = (_Float16*)alloc((size_t)n * 32 * 2);
  _Float16* h       = (_Float16*)alloc((size_t)n * HID * 2);
  _Float16* QKV     = (_Float16*)alloc((size_t)n * QKVW * 2);
  _Float16* ao      = (_Float16*)alloc((size_t)n * HID * 2);
  _Float16* inWt    = (_Float16*)alloc((size_t)32 * HID * 2);
  _Float16* qkvWt   = (_Float16*)alloc((size_t)NL * QKVW * (HID + TD) * 2);
  float*    qkvb    = (float*)alloc((size_t)NL * QKVW * 4);
  _Float16* oWt     = (_Float16*)alloc((size_t)NL * HID * HID * 2);
  int*      deg     = (int*)alloc((size_t)n * 4);
  int*      cursor  = (int*)alloc((size_t)n * 4);
  int*      row_ptr = (int*)alloc((size_t)(n + 1) * 4);
  int*      colbuf  = (int*)alloc((size_t)e * 4);
  int*      bsum    = (int*)alloc((size_t)nb * 4);
  int*      boff    = (int*)alloc((size_t)nb * 4);
  float*    partial = (float*)alloc((size_t)256 * HID * 4);
  float*    mmf     = (float*)alloc(256);

  int b256 = 256;
  hipLaunchKernelGGL(k_tsmm, dim3(1), dim3(1024), 0, stream, ts, mmf, deg, n);
  hipLaunchKernelGGL(k_enc, dim3((n * 64 + 255) / 256), dim3(b256), 0, stream,
                     ts, freq, mmf, x, tfh, xh, n);
  {
    int total = 32 * HID + NL * QKVW * (HID + TD) + NL * QKVW + NL * HID * HID;
    hipLaunchKernelGGL(k_prep, dim3((total + 255) / 256), dim3(b256), 0, stream,
                       inW, qW, kW, vW, oW, qb, kb, vb, inWt, qkvWt, qkvb, oWt);
  }
  hipLaunchKernelGGL(k_count, dim3((e + 255) / 256), dim3(b256), 0, stream, dst, deg, e);
  hipLaunchKernelGGL(k_scan_part, dim3(nb), dim3(b256), 0, stream, deg, bsum, n);
  hipLaunchKernelGGL(k_scan_mid, dim3(1), dim3(64), 0, stream, bsum, boff, nb);
  hipLaunchKernelGGL(k_scan_apply, dim3(nb), dim3(b256), 0, stream, deg, boff, row_ptr, cursor, n, e);
  hipLaunchKernelGGL(k_scatter, dim3((e + 255) / 256), dim3(b256), 0, stream, src, dst, row_ptr, cursor, colbuf, e);

  dim3 ggrid_h(HID / 64, (n + 127) / 128);
  dim3 ggrid_qkv(QKVW / 64, (n + 127) / 128);
  hipLaunchKernelGGL(k_gemm_f16, ggrid_h, dim3(b256), 0, stream,
                     xh, 32, xh, 32, inWt, inb, h, n, HID, 32, 0);

  for (int l = 0; l < NL; ++l) {
    const _Float16* qkvWtl = qkvWt + (size_t)l * QKVW * (HID + TD);
    const float*    qkvbl  = qkvb + (size_t)l * QKVW;
    const _Float16* oWtl   = oWt + (size_t)l * HID * HID;
    hipLaunchKernelGGL(k_gemm_f16, ggrid_qkv, dim3(b256), 0, stream,
                       h, HID, tfh, TD, qkvWtl, qkvbl, QKV, n, QKVW, HID + TD, 0);
    hipLaunchKernelGGL(k_attn, dim3((n + 3) / 4), dim3(b256), 0, stream,
                       QKV, row_ptr, colbuf, ao, n);
    hipLaunchKernelGGL(k_gemm_f16, ggrid_h, dim3(b256), 0, stream,
                       ao, HID, ao, HID, oWtl, ob + l * HID, h, n, HID, HID, 1);
  }

  hipLaunchKernelGGL(k_pool_partial, dim3(256), dim3(b256), 0, stream, h, partial, n);
  hipLaunchKernelGGL(k_final, dim3(1), dim3(b256), 0, stream, partial, c1W, c1b, c2W, c2b, (float*)d_out, n);
}

// Round 7
// 480.420 us; speedup vs baseline: 1.3210x; 1.1978x over previous
//
#include <hip/hip_runtime.h>
#include <math.h>

#define HID 256
#define TD 32
#define NL 3
#define C1DIM 128
#define OUTDIM 2
#define QKVW 768
#define KVSTRIDE 576

using half8  = __attribute__((ext_vector_type(8))) _Float16;
using half4v = __attribute__((ext_vector_type(4))) _Float16;
using half2v = __attribute__((ext_vector_type(2))) _Float16;
using f32x4  = __attribute__((ext_vector_type(4))) float;

typedef __attribute__((address_space(1))) void gbl_void_t;
typedef __attribute__((address_space(3))) void lds_void_t;

__device__ __forceinline__ void load16_to_lds(const void* g, void* l) {
  __builtin_amdgcn_global_load_lds((const gbl_void_t*)g, (lds_void_t*)l, 16, 0, 0);
}

__device__ __forceinline__ int sdot4i(unsigned a, unsigned b, int acc) {
#if __has_builtin(__builtin_amdgcn_sdot4)
  return __builtin_amdgcn_sdot4((int)a, (int)b, acc, false);
#else
#pragma unroll
  for (int i = 0; i < 4; ++i)
    acc += (int)(signed char)(a >> (8 * i)) * (int)(signed char)(b >> (8 * i));
  return acc;
#endif
}

__device__ __forceinline__ void i8x4_to_f32(unsigned w, float* o) {
  o[0] = (float)(int)(signed char)(w);
  o[1] = (float)(int)(signed char)(w >> 8);
  o[2] = (float)(int)(signed char)(w >> 16);
  o[3] = (float)(int)(signed char)(w >> 24);
}

// ---------- setup: ts min/max (single block) + zero deg ----------
__global__ __launch_bounds__(1024) void k_tsmm(const float* __restrict__ ts,
                                               float* __restrict__ mmf,
                                               int* __restrict__ deg, int n) {
  int t = threadIdx.x;
  float lmin = INFINITY, lmax = -INFINITY;
  for (int i = t; i < n; i += 1024) {
    float v = ts[i];
    lmin = fminf(lmin, v);
    lmax = fmaxf(lmax, v);
    deg[i] = 0;
  }
#pragma unroll
  for (int off = 32; off >= 1; off >>= 1) {
    lmin = fminf(lmin, __shfl_xor(lmin, off));
    lmax = fmaxf(lmax, __shfl_xor(lmax, off));
  }
  __shared__ float wmin[16], wmax[16];
  int lane = t & 63, w = t >> 6;
  if (lane == 0) { wmin[w] = lmin; wmax[w] = lmax; }
  __syncthreads();
  if (t == 0) {
    float a = INFINITY, b = -INFINITY;
    for (int i = 0; i < 16; ++i) { a = fminf(a, wmin[i]); b = fmaxf(b, wmax[i]); }
    mmf[0] = a; mmf[1] = b;
  }
}

// ---------- merged time encoding + x conversion ----------
__global__ void k_enc(const float* __restrict__ ts, const float* __restrict__ freq,
                      const float* __restrict__ mmf, const float* __restrict__ x,
                      _Float16* __restrict__ tfh, _Float16* __restrict__ xh, int n) {
  int idx = blockIdx.x * blockDim.x + threadIdx.x;
  int nt = n * TD;
  if (idx < nt) {
    int node = idx >> 5, j = idx & 31;
    float t = (ts[node] - mmf[0]) / (mmf[1] - mmf[0] + 1e-8f);
    float w = t * freq[j & 15];
    tfh[idx] = (_Float16)((j < 16) ? cosf(w) : sinf(w));
  } else if (idx < nt + n * 32) {
    int i2 = idx - nt;
    xh[i2] = (_Float16)x[i2];
  }
}

// ---------- merged weight prep ----------
__global__ void k_prep(const float* __restrict__ inW, const float* __restrict__ qW,
                       const float* __restrict__ kW, const float* __restrict__ vW,
                       const float* __restrict__ oW, const float* __restrict__ qb,
                       const float* __restrict__ kb, const float* __restrict__ vb,
                       _Float16* __restrict__ inWt, _Float16* __restrict__ qkvWt,
                       float* __restrict__ qkvb, _Float16* __restrict__ oWt) {
  int idx = blockIdx.x * blockDim.x + threadIdx.x;
  const int S0 = 32 * HID;
  const int KQ = HID + TD;
  const int S1 = NL * QKVW * KQ;
  const int S2 = NL * QKVW;
  const int S3 = NL * HID * HID;
  if (idx < S0) {
    int nrow = idx / 32, k = idx - nrow * 32;
    inWt[idx] = (_Float16)inW[k * HID + nrow];
  } else if ((idx -= S0) < S1) {
    int l = idx / (QKVW * KQ);
    int rem = idx - l * (QKVW * KQ);
    int nrow = rem / KQ;
    int k = rem - nrow * KQ;
    float v;
    if (nrow < 256)      v = qW[(size_t)l * KQ * HID + (size_t)k * HID + nrow];
    else if (nrow < 512) v = kW[(size_t)l * KQ * HID + (size_t)k * HID + (nrow - 256)];
    else                 v = (k < HID) ? vW[(size_t)l * HID * HID + (size_t)k * HID + (nrow - 512)] : 0.f;
    qkvWt[idx] = (_Float16)v;
  } else if ((idx -= S1) < S2) {
    int l = idx / QKVW;
    int j = idx - l * QKVW;
    float v;
    if (j < 256)      v = qb[l * HID + j];
    else if (j < 512) v = kb[l * HID + (j - 256)];
    else              v = vb[l * HID + (j - 512)];
    qkvb[idx] = v;
  } else if ((idx -= S2) < S3) {
    int l = idx / (HID * HID);
    int rem = idx - l * (HID * HID);
    int nrow = rem / HID;
    int k = rem - nrow * HID;
    oWt[idx] = (_Float16)oW[(size_t)l * HID * HID + (size_t)k * HID + nrow];
  }
}

__global__ void k_count(const int* __restrict__ dst, int* deg, int e) {
  int i = blockIdx.x * blockDim.x + threadIdx.x;
  if (i < e) atomicAdd(&deg[dst[i]], 1);
}

// ---------- 3-kernel scan ----------
__global__ __launch_bounds__(256) void k_scan_part(const int* __restrict__ deg,
                                                   int* __restrict__ bsum, int n) {
  int t = threadIdx.x;
  int idx = blockIdx.x * 256 + t;
  int v = (idx < n) ? deg[idx] : 0;
  int lane = t & 63, w = t >> 6;
  int x = v;
#pragma unroll
  for (int off = 1; off < 64; off <<= 1) {
    int y = __shfl_up(x, off);
    if (lane >= off) x += y;
  }
  __shared__ int ws[4];
  if (lane == 63) ws[w] = x;
  __syncthreads();
  if (t == 0) bsum[blockIdx.x] = ws[0] + ws[1] + ws[2] + ws[3];
}

__global__ __launch_bounds__(64) void k_scan_mid(const int* __restrict__ bsum,
                                                 int* __restrict__ boff, int nb) {
  int lane = threadIdx.x;
  int carry = 0;
  for (int base = 0; base < nb; base += 64) {
    int i = base + lane;
    int v = (i < nb) ? bsum[i] : 0;
    int x = v;
#pragma unroll
    for (int off = 1; off < 64; off <<= 1) {
      int y = __shfl_up(x, off);
      if (lane >= off) x += y;
    }
    if (i < nb) boff[i] = carry + x - v;
    carry += __shfl(x, 63);
  }
}

__global__ __launch_bounds__(256) void k_scan_apply(const int* __restrict__ deg,
                                                    const int* __restrict__ boff,
                                                    int* __restrict__ row_ptr,
                                                    int* __restrict__ cursor, int n, int e) {
  int t = threadIdx.x;
  int idx = blockIdx.x * 256 + t;
  int v = (idx < n) ? deg[idx] : 0;
  int lane = t & 63, w = t >> 6;
  int x = v;
#pragma unroll
  for (int off = 1; off < 64; off <<= 1) {
    int y = __shfl_up(x, off);
    if (lane >= off) x += y;
  }
  __shared__ int ws[4];
  if (lane == 63) ws[w] = x;
  __syncthreads();
  int wpre = 0;
  for (int i = 0; i < w; ++i) wpre += ws[i];
  if (idx < n) {
    row_ptr[idx] = boff[blockIdx.x] + wpre + x - v;
    cursor[idx] = 0;
  }
  if (idx == 0) row_ptr[n] = e;
}

__global__ void k_scatter(const int* __restrict__ src, const int* __restrict__ dst,
                          const int* __restrict__ row_ptr, int* cursor,
                          int* __restrict__ colbuf, int e) {
  int i = blockIdx.x * blockDim.x + threadIdx.x;
  if (i >= e) return;
  int d = dst[i];
  int p = atomicAdd(&cursor[d], 1);
  colbuf[row_ptr[d] + p] = src[i];
}

// ---------- fp16 MFMA GEMM (128x64 tile, BK=32, 4 waves) ----------
__global__ __launch_bounds__(256) void k_gemm_f16(
    const _Float16* __restrict__ A1, int K1,
    const _Float16* __restrict__ A2, int K2,
    const _Float16* __restrict__ Bt,
    const float* __restrict__ bias,
    _Float16* __restrict__ C,
    int M, int Ncols, int Ktot, int act) {
  __shared__ half8 smem8[2 * 768];
  char* smem = (char*)smem8;
  const int tid = threadIdx.x;
  const int lane = tid & 63, wave = tid >> 6;
  const int wm = wave >> 1, wn = wave & 1;
  const int row0 = blockIdx.y * 128;
  const int col0 = blockIdx.x * 64;

  auto stage = [&](int buf, int k0) {
    char* sA = smem + buf * 12288;
    char* sB = sA + 8192;
#pragma unroll
    for (int i = 0; i < 2; ++i) {
      int kg = i * 2 + (wave >> 1);
      int row = (wave & 1) * 64 + lane;
      int grow = row0 + row; if (grow > M - 1) grow = M - 1;
      int k = k0 + kg * 8;
      const _Float16* src = (k < K1) ? (A1 + (size_t)grow * K1 + k)
                                     : (A2 + (size_t)grow * K2 + (k - K1));
      load16_to_lds(src, sA + (i * 256 + wave * 64) * 16);
    }
    {
      const _Float16* src = Bt + (size_t)(col0 + lane) * Ktot + k0 + wave * 8;
      load16_to_lds(src, sB + wave * 64 * 16);
    }
  };

  f32x4 acc[4][2];
#pragma unroll
  for (int mf = 0; mf < 4; ++mf)
#pragma unroll
    for (int nf = 0; nf < 2; ++nf) acc[mf][nf] = f32x4{0.f, 0.f, 0.f, 0.f};

  const int nsteps = Ktot >> 5;
  int cur = 0;
  stage(0, 0);
  __syncthreads();
  for (int st = 0; st < nsteps; ++st) {
    if (st + 1 < nsteps) stage(cur ^ 1, (st + 1) * 32);
    char* sA = smem + cur * 12288;
    char* sB = sA + 8192;
    half8 af[4], bf[2];
#pragma unroll
    for (int mf = 0; mf < 4; ++mf) {
      int slot = (lane >> 4) * 128 + wm * 64 + mf * 16 + (lane & 15);
      af[mf] = *(const half8*)(sA + slot * 16);
    }
#pragma unroll
    for (int nf = 0; nf < 2; ++nf) {
      int slot = (lane >> 4) * 64 + wn * 32 + nf * 16 + (lane & 15);
      bf[nf] = *(const half8*)(sB + slot * 16);
    }
#pragma unroll
    for (int mf = 0; mf < 4; ++mf)
#pragma unroll
      for (int nf = 0; nf < 2; ++nf)
        acc[mf][nf] = __builtin_amdgcn_mfma_f32_16x16x32_f16(af[mf], bf[nf], acc[mf][nf], 0, 0, 0);
    __syncthreads();
    cur ^= 1;
  }

  const int rbase = row0 + wm * 64 + (lane >> 4) * 4;
  const int cbase = col0 + wn * 32 + (lane & 15);
#pragma unroll
  for (int nf = 0; nf < 2; ++nf) {
    int col = cbase + nf * 16;
    float bv = bias[col];
#pragma unroll
    for (int mf = 0; mf < 4; ++mf) {
#pragma unroll
      for (int r = 0; r < 4; ++r) {
        int row = rbase + mf * 16 + r;
        if (row < M) {
          float v = acc[mf][nf][r] + bv;
          if (act == 1) v = (v > 0.f) ? v : expm1f(v);
          C[(size_t)row * Ncols + col] = (_Float16)v;
        }
      }
    }
  }
}

// ---------- K/V fp16 -> int8 per-node-per-head quantization ----------
// layout per node (stride 576): [K int8 0..255][V int8 256..511][(sk,sv) f16 pairs x8 512..543]
// one 32-thread group per node; 8 nodes/block
__global__ __launch_bounds__(256) void k_cvt8(const _Float16* __restrict__ QKV,
                                              unsigned char* __restrict__ KV8, int n) {
  int node = blockIdx.x * 8 + (threadIdx.x >> 5);
  if (node >= n) return;
  int t32 = threadIdx.x & 31;
  const _Float16* base = QKV + (size_t)node * QKVW + t32 * 8;
  half8 kh = *(const half8*)(base + 256);
  half8 vh = *(const half8*)(base + 512);
  float kf[8], vf[8];
  float kmax = 0.f, vmax = 0.f;
#pragma unroll
  for (int j = 0; j < 8; ++j) {
    kf[j] = (float)kh[j]; kmax = fmaxf(kmax, fabsf(kf[j]));
    vf[j] = (float)vh[j]; vmax = fmaxf(vmax, fabsf(vf[j]));
  }
  // per-head (quad of 4 threads) max
  kmax = fmaxf(kmax, __shfl_xor(kmax, 1)); kmax = fmaxf(kmax, __shfl_xor(kmax, 2));
  vmax = fmaxf(vmax, __shfl_xor(vmax, 1)); vmax = fmaxf(vmax, __shfl_xor(vmax, 2));
  float kinv = (kmax > 0.f) ? (127.f / kmax) : 0.f;
  float vinv = (vmax > 0.f) ? (127.f / vmax) : 0.f;
  unsigned kp0 = 0, kp1 = 0, vp0 = 0, vp1 = 0;
#pragma unroll
  for (int j = 0; j < 4; ++j) {
    kp0 |= ((unsigned)((int)rintf(kf[j] * kinv)) & 255u) << (8 * j);
    kp1 |= ((unsigned)((int)rintf(kf[j + 4] * kinv)) & 255u) << (8 * j);
    vp0 |= ((unsigned)((int)rintf(vf[j] * vinv)) & 255u) << (8 * j);
    vp1 |= ((unsigned)((int)rintf(vf[j + 4] * vinv)) & 255u) << (8 * j);
  }
  unsigned char* out = KV8 + (size_t)node * KVSTRIDE;
  *(uint2*)(out + t32 * 8) = uint2{kp0, kp1};
  *(uint2*)(out + 256 + t32 * 8) = uint2{vp0, vp1};
  if ((t32 & 3) == 0) {
    half2v sp;
    sp.x = (_Float16)(kmax * (1.f / 127.f));
    sp.y = (_Float16)(vmax * (1.f / 127.f));
    *(half2v*)(out + 512 + (t32 >> 2) * 4) = sp;
  }
}

// ---------- attention: int8 K/V, 2 groups per node, LSE-merge in LDS ----------
// block = 256 = 8 groups of 32 threads; 4 nodes/block
__global__ __launch_bounds__(256) void k_attn(const _Float16* __restrict__ QKV,
                                              const unsigned char* __restrict__ KV8,
                                              const int* __restrict__ row_ptr,
                                              const int* __restrict__ colbuf,
                                              _Float16* __restrict__ out, int n) {
  __shared__ float sm_m[4][8], sm_s[4][8];
  __shared__ float sm_a[4][32][9];
  int tid = threadIdx.x;
  int g = tid >> 5, t32 = tid & 31;
  int nl = g >> 1, hf = g & 1;
  int node = blockIdx.x * 4 + nl;
  bool act = node < n;
  int beg = 0, end = 0;
  if (act) { beg = row_ptr[node]; end = row_ptr[node + 1]; }
  int mid = beg + ((end - beg + 1) >> 1);
  int lo = hf ? mid : beg;
  int hi = hf ? end : mid;
  int d = t32 * 8;
  const float scale = 0.17677669529663687f;  // 1/sqrt(32)

  // quantize Q (scale folded in) per node/head
  float qf[8] = {0.f, 0.f, 0.f, 0.f, 0.f, 0.f, 0.f, 0.f};
  if (act) {
    half8 qh = *(const half8*)(QKV + (size_t)node * QKVW + d);
#pragma unroll
    for (int j = 0; j < 8; ++j) qf[j] = (float)qh[j] * scale;
  }
  float qmax = 0.f;
#pragma unroll
  for (int j = 0; j < 8; ++j) qmax = fmaxf(qmax, fabsf(qf[j]));
  qmax = fmaxf(qmax, __shfl_xor(qmax, 1));
  qmax = fmaxf(qmax, __shfl_xor(qmax, 2));
  float qinv = (qmax > 0.f) ? (127.f / qmax) : 0.f;
  float sq = qmax * (1.f / 127.f);
  unsigned q8x = 0, q8y = 0;
#pragma unroll
  for (int j = 0; j < 4; ++j) {
    q8x |= ((unsigned)((int)rintf(qf[j] * qinv)) & 255u) << (8 * j);
    q8y |= ((unsigned)((int)rintf(qf[j + 4] * qinv)) & 255u) << (8 * j);
  }

  float m = -INFINITY, s = 0.f;
  float a[8] = {0.f, 0.f, 0.f, 0.f, 0.f, 0.f, 0.f, 0.f};
  int scoff = 512 + (t32 >> 2) * 4;

  for (int i = lo; i < hi; i += 4) {
    uint2 kb[4], vb[4];
    float skj[4], svj[4];
#pragma unroll
    for (int j = 0; j < 4; ++j) {
      int ii = i + j; if (ii > hi - 1) ii = hi - 1;
      int sn = colbuf[ii];
      const unsigned char* b = KV8 + (size_t)sn * KVSTRIDE;
      kb[j] = *(const uint2*)(b + t32 * 8);
      vb[j] = *(const uint2*)(b + 256 + t32 * 8);
      unsigned scw = *(const unsigned*)(b + scoff);
      union { unsigned u; half2v h; } sc; sc.u = scw;
      skj[j] = (float)sc.h.x;
      svj[j] = (float)sc.h.y;
    }
    float p[4];
#pragma unroll
    for (int j = 0; j < 4; ++j) {
      int idot = sdot4i(kb[j].x, q8x, 0);
      idot = sdot4i(kb[j].y, q8y, idot);
      p[j] = (float)idot;
    }
#pragma unroll
    for (int j = 0; j < 4; ++j) {
      p[j] += __shfl_xor(p[j], 1);
      p[j] += __shfl_xor(p[j], 2);
      p[j] *= sq * skj[j];
      if (i + j >= hi) p[j] = -INFINITY;  // tail mask (j=0 always real)
    }
#pragma unroll
    for (int j = 0; j < 4; ++j) {
      float vf[8];
      i8x4_to_f32(vb[j].x, vf);
      i8x4_to_f32(vb[j].y, vf + 4);
      float sc_ = p[j];
      if (sc_ <= m) {
        float e2 = __expf(sc_ - m);
        s += e2;
        float ev = e2 * svj[j];
#pragma unroll
        for (int q = 0; q < 8; ++q) a[q] = fmaf(ev, vf[q], a[q]);
      } else {
        float f = __expf(m - sc_);  // m=-inf on first real edge -> f=0
        s = s * f + 1.f;
#pragma unroll
        for (int q = 0; q < 8; ++q) a[q] = fmaf(a[q], f, svj[j] * vf[q]);
        m = sc_;
      }
    }
  }

  if (hf == 1 && act) {
    if ((t32 & 3) == 0) { sm_m[nl][t32 >> 2] = m; sm_s[nl][t32 >> 2] = s; }
#pragma unroll
    for (int q = 0; q < 8; ++q) sm_a[nl][t32][q] = a[q];
  }
  __syncthreads();
  if (hf == 0 && act) {
    float m1 = sm_m[nl][t32 >> 2], s1 = sm_s[nl][t32 >> 2];
    float M = fmaxf(m, m1);
    float f0 = (s > 0.f) ? __expf(m - M) : 0.f;
    float f1 = (s1 > 0.f) ? __expf(m1 - M) : 0.f;
    float S = s * f0 + s1 * f1;
    float inv = (S > 0.f) ? (1.f / S) : 0.f;
    half8 o;
#pragma unroll
    for (int q = 0; q < 8; ++q) o[q] = (_Float16)((a[q] * f0 + sm_a[nl][t32][q] * f1) * inv);
    *(half8*)(out + (size_t)node * HID + d) = o;
  }
}

// ---------- pooling + classifier ----------
__global__ __launch_bounds__(256) void k_pool_partial(const _Float16* __restrict__ h,
                                                      float* __restrict__ partial, int n) {
  int b = blockIdx.x, t = threadIdx.x;
  float s = 0.f;
  for (int r = b; r < n; r += 256) s += (float)h[(size_t)r * HID + t];
  partial[b * HID + t] = s;
}

__global__ __launch_bounds__(256) void k_final(const float* __restrict__ partial,
                                               const float* __restrict__ c1W,
                                               const float* __restrict__ c1b,
                                               const float* __restrict__ c2W,
                                               const float* __restrict__ c2b,
                                               float* __restrict__ out, int n) {
  __shared__ float gl[HID];
  __shared__ float r1[C1DIM];
  int t = threadIdx.x;
  float s = 0.f;
  for (int b = 0; b < 256; b++) s += partial[b * HID + t];
  gl[t] = s / (float)n;
  __syncthreads();
  if (t < C1DIM) {
    float a = c1b[t];
    for (int k = 0; k < HID; k++) a += gl[k] * c1W[k * C1DIM + t];
    r1[t] = fmaxf(a, 0.f);
  }
  __syncthreads();
  if (t < OUTDIM) {
    float a = c2b[t];
    for (int k = 0; k < C1DIM; k++) a += r1[k] * c2W[k * OUTDIM + t];
    out[t] = a;
  }
}

// ---------- host launcher ----------
extern "C" void kernel_launch(void* const* d_in, const int* in_sizes, int n_in,
                              void* d_out, int out_size, void* d_ws, size_t ws_size,
                              hipStream_t stream) {
  const float* x    = (const float*)d_in[0];
  const float* ts   = (const float*)d_in[1];
  const int*   ei   = (const int*)d_in[2];
  const float* freq = (const float*)d_in[4];
  const float* inW  = (const float*)d_in[5];
  const float* inb  = (const float*)d_in[6];
  const float* qW   = (const float*)d_in[7];
  const float* qb   = (const float*)d_in[8];
  const float* kW   = (const float*)d_in[9];
  const float* kb   = (const float*)d_in[10];
  const float* vW   = (const float*)d_in[11];
  const float* vb   = (const float*)d_in[12];
  const float* oW   = (const float*)d_in[13];
  const float* ob   = (const float*)d_in[14];
  const float* c1W  = (const float*)d_in[15];
  const float* c1b  = (const float*)d_in[16];
  const float* c2W  = (const float*)d_in[17];
  const float* c2b  = (const float*)d_in[18];

  int n = in_sizes[1];
  int e = in_sizes[2] / 2;
  const int* src = ei;
  const int* dst = ei + e;
  int nb = (n + 255) / 256;

  char* w = (char*)d_ws;
  size_t off = 0;
  auto alloc = [&](size_t bytes) -> char* {
    char* p = w + off;
    off = (off + bytes + 255) & ~(size_t)255;
    return p;
  };
  _Float16* tfh     = (_Float16*)alloc((size_t)n * TD * 2);
  _Float16* xh      = (_Float16*)alloc((size_t)n * 32 * 2);
  _Float16* h       = (_Float16*)alloc((size_t)n * HID * 2);
  _Float16* QKV     = (_Float16*)alloc((size_t)n * QKVW * 2);
  unsigned char* KV8 = (unsigned char*)alloc((size_t)n * KVSTRIDE);
  _Float16* ao      = (_Float16*)alloc((size_t)n * HID * 2);
  _Float16* inWt    = (_Float16*)alloc((size_t)32 * HID * 2);
  _Float16* qkvWt   = (_Float16*)alloc((size_t)NL * QKVW * (HID + TD) * 2);
  float*    qkvb    = (float*)alloc((size_t)NL * QKVW * 4);
  _Float16* oWt     = (_Float16*)alloc((size_t)NL * HID * HID * 2);
  int*      deg     = (int*)alloc((size_t)n * 4);
  int*      cursor  = (int*)alloc((size_t)n * 4);
  int*      row_ptr = (int*)alloc((size_t)(n + 1) * 4);
  int*      colbuf  = (int*)alloc((size_t)e * 4);
  int*      bsum    = (int*)alloc((size_t)nb * 4);
  int*      boff    = (int*)alloc((size_t)nb * 4);
  float*    partial = (float*)alloc((size_t)256 * HID * 4);
  float*    mmf     = (float*)alloc(256);

  int b256 = 256;
  hipLaunchKernelGGL(k_tsmm, dim3(1), dim3(1024), 0, stream, ts, mmf, deg, n);
  hipLaunchKernelGGL(k_enc, dim3((n * 64 + 255) / 256), dim3(b256), 0, stream,
                     ts, freq, mmf, x, tfh, xh, n);
  {
    int total = 32 * HID + NL * QKVW * (HID + TD) + NL * QKVW + NL * HID * HID;
    hipLaunchKernelGGL(k_prep, dim3((total + 255) / 256), dim3(b256), 0, stream,
                       inW, qW, kW, vW, oW, qb, kb, vb, inWt, qkvWt, qkvb, oWt);
  }
  hipLaunchKernelGGL(k_count, dim3((e + 255) / 256), dim3(b256), 0, stream, dst, deg, e);
  hipLaunchKernelGGL(k_scan_part, dim3(nb), dim3(b256), 0, stream, deg, bsum, n);
  hipLaunchKernelGGL(k_scan_mid, dim3(1), dim3(64), 0, stream, bsum, boff, nb);
  hipLaunchKernelGGL(k_scan_apply, dim3(nb), dim3(b256), 0, stream, deg, boff, row_ptr, cursor, n, e);
  hipLaunchKernelGGL(k_scatter, dim3((e + 255) / 256), dim3(b256), 0, stream, src, dst, row_ptr, cursor, colbuf, e);

  dim3 ggrid_h(HID / 64, (n + 127) / 128);
  dim3 ggrid_qkv(QKVW / 64, (n + 127) / 128);
  hipLaunchKernelGGL(k_gemm_f16, ggrid_h, dim3(b256), 0, stream,
                     xh, 32, xh, 32, inWt, inb, h, n, HID, 32, 0);

  for (int l = 0; l < NL; ++l) {
    const _Float16* qkvWtl = qkvWt + (size_t)l * QKVW * (HID + TD);
    const float*    qkvbl  = qkvb + (size_t)l * QKVW;
    const _Float16* oWtl   = oWt + (size_t)l * HID * HID;
    hipLaunchKernelGGL(k_gemm_f16, ggrid_qkv, dim3(b256), 0, stream,
                       h, HID, tfh, TD, qkvWtl, qkvbl, QKV, n, QKVW, HID + TD, 0);
    hipLaunchKernelGGL(k_cvt8, dim3((n + 7) / 8), dim3(b256), 0, stream,
                       QKV, KV8, n);
    hipLaunchKernelGGL(k_attn, dim3((n + 3) / 4), dim3(b256), 0, stream,
                       QKV, KV8, row_ptr, colbuf, ao, n);
    hipLaunchKernelGGL(k_gemm_f16, ggrid_h, dim3(b256), 0, stream,
                       ao, HID, ao, HID, oWtl, ob + l * HID, h, n, HID, HID, 1);
  }

  hipLaunchKernelGGL(k_pool_partial, dim3(256), dim3(b256), 0, stream, h, partial, n);
  hipLaunchKernelGGL(k_final, dim3(1), dim3(b256), 0, stream, partial, c1W, c1b, c2W, c2b, (float*)d_out, n);
}